// Round 4
// baseline (142.690 us; speedup 1.0000x reference)
//
#include <hip/hip_runtime.h>

typedef __bf16 bf16x8 __attribute__((ext_vector_type(8)));
typedef float  f32x4  __attribute__((ext_vector_type(4)));
typedef unsigned short u16;
typedef unsigned int   u32;

__device__ __forceinline__ float b2f(u16 u) {
    u32 x = ((u32)u) << 16;
    return __builtin_bit_cast(float, x);
}
__device__ __forceinline__ u16 f2b(float f) {
    u32 x = __builtin_bit_cast(u32, f);
    x += 0x7fffu + ((x >> 16) & 1u);   // RNE
    return (u16)(x >> 16);
}

// ---------------------------------------------------------------------------
// Kernel 1: convert x, [wq;wk;wv], wo  f32 -> bf16  (vectorized x4)
// ---------------------------------------------------------------------------
__global__ void convert_kernel(const float* __restrict__ x, const float* __restrict__ wq,
                               const float* __restrict__ wk, const float* __restrict__ wv,
                               const float* __restrict__ wo,
                               u16* __restrict__ xb, u16* __restrict__ wcat, u16* __restrict__ wob)
{
    long i4 = (long)blockIdx.x * 256 + threadIdx.x;   // 0..3670015
    long e = i4 * 4;
    const float* src; u16* dst;
    if (e < 4194304) { src = x + e; dst = xb + e; }
    else if (e < 10485760) {
        long j = e - 4194304;
        dst = wcat + j;
        if (j < 4194304)      src = wq + j;
        else if (j < 5242880) src = wk + (j - 4194304);
        else                  src = wv + (j - 5242880);
    } else {
        long j = e - 10485760;
        src = wo + j; dst = wob + j;
    }
    float4 v = *(const float4*)src;
    uint2 pk;
    pk.x = (u32)f2b(v.x) | ((u32)f2b(v.y) << 16);
    pk.y = (u32)f2b(v.z) | ((u32)f2b(v.w) << 16);
    *(uint2*)dst = pk;
}

// ---------------------------------------------------------------------------
// Kernel 2: bf16 GEMM  C[M][N] f32 = A[M][K] * B[N][K]^T
// 128x128 tile, BK=64, 512 threads = 8 waves (2M x 4N), wave = 64x32 out.
// ---------------------------------------------------------------------------
__global__ __launch_bounds__(512) void gemm_bt_kernel(
    const u16* __restrict__ A, const u16* __restrict__ B,
    float* __restrict__ C, int M, int N, int K)
{
    __shared__ u16 As[128 * 64];
    __shared__ u16 Bs[128 * 64];
    const int tid  = threadIdx.x;
    const int lane = tid & 63;
    const int wave = tid >> 6;
    const int waveM = wave >> 2, waveN = wave & 3;
    const int tm = blockIdx.y * 128;
    const int tn = blockIdx.x * 128;

    f32x4 acc[4][2];
#pragma unroll
    for (int i = 0; i < 4; ++i)
#pragma unroll
        for (int j = 0; j < 2; ++j) acc[i][j] = f32x4{0.f, 0.f, 0.f, 0.f};

    const int frow = lane & 15;
    const int fk   = (lane >> 4) * 8;

    for (int kt = 0; kt < K; kt += 64) {
#pragma unroll
        for (int c = 0; c < 2; ++c) {
            int idx = c * 512 + tid;
            int row = idx >> 3;
            int blk = (idx & 7) ^ (row & 7);
            const u16* srcA = A + (size_t)(tm + row) * K + kt + blk * 8;
            const u16* srcB = B + (size_t)(tn + row) * K + kt + blk * 8;
            u16* dstA = As + (size_t)(c * 512 + wave * 64) * 8;
            u16* dstB = Bs + (size_t)(c * 512 + wave * 64) * 8;
            __builtin_amdgcn_global_load_lds((const __attribute__((address_space(1))) void*)srcA,
                                             (__attribute__((address_space(3))) void*)dstA, 16, 0, 0);
            __builtin_amdgcn_global_load_lds((const __attribute__((address_space(1))) void*)srcB,
                                             (__attribute__((address_space(3))) void*)dstB, 16, 0, 0);
        }
        __syncthreads();
#pragma unroll
        for (int kk = 0; kk < 64; kk += 32) {
            bf16x8 af[4], bfr[2];
#pragma unroll
            for (int m = 0; m < 4; ++m) {
                int r  = waveM * 64 + m * 16 + frow;
                int kb_ = ((kk + fk) >> 3) ^ (r & 7);
                af[m] = *(const bf16x8*)&As[r * 64 + kb_ * 8];
            }
#pragma unroll
            for (int n = 0; n < 2; ++n) {
                int r  = waveN * 32 + n * 16 + frow;
                int kb_ = ((kk + fk) >> 3) ^ (r & 7);
                bfr[n] = *(const bf16x8*)&Bs[r * 64 + kb_ * 8];
            }
#pragma unroll
            for (int m = 0; m < 4; ++m)
#pragma unroll
                for (int n = 0; n < 2; ++n)
                    acc[m][n] = __builtin_amdgcn_mfma_f32_16x16x32_bf16(af[m], bfr[n], acc[m][n], 0, 0, 0);
        }
        __syncthreads();
    }
    const int rb = tm + waveM * 64;
    const int cb = tn + waveN * 32;
#pragma unroll
    for (int m = 0; m < 4; ++m)
#pragma unroll
        for (int n = 0; n < 2; ++n)
#pragma unroll
            for (int r = 0; r < 4; ++r) {
                int row = rb + m * 16 + (lane >> 4) * 4 + r;
                int col = cb + n * 16 + (lane & 15);
                C[(size_t)row * N + col] = acc[m][n][r];
            }
}

// ---------------------------------------------------------------------------
// Kernel 3: SSM + residual + RoPE (unchanged)
// ---------------------------------------------------------------------------
__global__ void ssm_rope_kernel(const float* __restrict__ c1, const float* __restrict__ fc,
                                const float* __restrict__ alk, const float* __restrict__ bk,
                                const float* __restrict__ ck,
                                const float* __restrict__ alv, const float* __restrict__ bv,
                                const float* __restrict__ cv,
                                u16* __restrict__ qb, u16* __restrict__ kb, u16* __restrict__ vb)
{
    int gi = blockIdx.x * 256 + threadIdx.x;
    if (gi < 2097152) {
        int s = gi >> 10, pg = gi & 1023;
        int i = pg & 63;
        int e0 = (pg >> 6) * 128 + 2 * i;
        float2 xv = *(const float2*)&c1[(size_t)s * 3072 + e0];
        float4 f = *(const float4*)&fc[((size_t)s * 64 + i) * 4];
        float q0 = xv.x * f.x - xv.y * f.z;
        float q1 = xv.x * f.z + xv.y * f.x;
        *(u32*)&qb[(size_t)s * 2048 + e0] = (u32)f2b(q0) | ((u32)f2b(q1) << 16);
    } else if (gi < 2097152 + 65536) {
        int ki = gi - 2097152;
        int chunk = ki >> 8, pr = ki & 255;
        int i = pr & 63;
        int e0 = (pr >> 6) * 128 + 2 * i;
        float z0 = alk[e0], z1 = alk[e0 + 1];
        float sp0 = z0 > 20.f ? z0 : log1pf(__expf(z0));
        float sp1 = z1 > 20.f ? z1 : log1pf(__expf(z1));
        float a0 = __expf(-sp0), a1 = __expf(-sp1);
        float b0 = bk[e0], b1 = bk[e0 + 1];
        float c0 = ck[e0], cc1 = ck[e0 + 1];
        float h0 = 0.f, h1 = 0.f;
#pragma unroll
        for (int tt = 0; tt < 8; ++tt) {
            int s = chunk * 8 + tt;
            float2 xv = *(const float2*)&c1[(size_t)s * 3072 + 2048 + e0];
            h0 = a0 * h0 + b0 * xv.x;
            h1 = a1 * h1 + b1 * xv.y;
            float y0 = c0 * h0 + xv.x;
            float y1 = cc1 * h1 + xv.y;
            float4 f = *(const float4*)&fc[((size_t)s * 64 + i) * 4];
            float k0 = y0 * f.x - y1 * f.z;
            float k1 = y0 * f.z + y1 * f.x;
            *(u32*)&kb[(size_t)s * 512 + e0] = (u32)f2b(k0) | ((u32)f2b(k1) << 16);
        }
    } else {
        int vi = gi - 2097152 - 65536;
        int chunk = vi >> 9, e = vi & 511;
        float z = alv[e];
        float sp = z > 20.f ? z : log1pf(__expf(z));
        float a = __expf(-sp);
        float b = bv[e], c = cv[e];
        float h = 0.f;
#pragma unroll
        for (int tt = 0; tt < 8; ++tt) {
            int s = chunk * 8 + tt;
            float xvv = c1[(size_t)s * 3072 + 2560 + e];
            h = a * h + b * xvv;
            vb[(size_t)s * 512 + e] = f2b(c * h + xvv);
        }
    }
}

// ---------------------------------------------------------------------------
// Kernel 4: compact boundary keys (pos = 8j+7, j<256):
//   kbc[kvh][j][d]  row-major K rows  (QK^T B-operand)
//   vbt[kvh][d][j]  transposed V      (PV    B-operand)
// ---------------------------------------------------------------------------
__global__ void compact_kernel(const u16* __restrict__ kb, const u16* __restrict__ vb,
                               u16* __restrict__ kbc, u16* __restrict__ vbt)
{
    int id = blockIdx.x * 256 + threadIdx.x;    // 131072
    int kvh = id >> 15, rem = id & 32767, j = rem >> 7, d = rem & 127;
    int src = (8 * j + 7) * 512 + kvh * 128 + d;
    kbc[(((kvh << 8) + j) << 7) + d] = kb[src];
    vbt[(((kvh << 7) + d) << 8) + j] = vb[src];
}

// ---------------------------------------------------------------------------
// Kernel 5: MFMA sparse attention, split-K across wave pairs.
// Block = (head, 64-query tile), 8 waves = (query-group qg, key-half).
// Each wave: 8 boundary frags (its 128 keys) + 1 extra frag, partial softmax,
// wave-private P->LDS, partial PV, then 2-way flash merge through LDS.
// ---------------------------------------------------------------------------
__global__ __launch_bounds__(512, 4) void attn_kernel(
    const u16* __restrict__ qb, const u16* __restrict__ kb, const u16* __restrict__ vb,
    const u16* __restrict__ kbc, const u16* __restrict__ vbt, u16* __restrict__ aout)
{
    __shared__ u16   p_main[8][2048];     // per-wave 16q x 128k bf16 P; reused as f32 merge buf
    __shared__ float p_ext[8][16][16];    // per-wave extra-col P
    __shared__ float p_ms[8][16][2];      // per-wave per-q {max, sum}

    const int w    = threadIdx.x >> 6;
    const int qg   = w >> 1;              // query group (16 queries)
    const int half = w & 1;               // key half (128 boundary keys)
    const int lane = threadIdx.x & 63;
    const int s    = lane & 15;
    const int g    = lane >> 4;
    const int h    = blockIdx.x >> 5;
    const int t0   = (blockIdx.x & 31) * 64;
    const int kvh  = h >> 2;
    const int qw   = t0 + qg * 16;

    // ---- Q A-fragments ----
    bf16x8 qa[4];
    {
        const u16* qr = qb + (size_t)(qw + s) * 2048 + h * 128 + g * 8;
#pragma unroll
        for (int kk = 0; kk < 4; ++kk) qa[kk] = *(const bf16x8*)&qr[kk * 32];
    }

    // ---- scores: 8 boundary frags (this half) + 1 extra frag ----
    f32x4 sf[9];
#pragma unroll
    for (int i = 0; i < 9; ++i) sf[i] = f32x4{0.f, 0.f, 0.f, 0.f};

    {
        const u16* kbase = kbc + ((size_t)kvh << 15) + (size_t)half * 16384;
#pragma unroll
        for (int fb = 0; fb < 8; ++fb) {
            const u16* kr = kbase + (size_t)(fb * 16 + s) * 128 + g * 8;
#pragma unroll
            for (int kk = 0; kk < 4; ++kk) {
                bf16x8 bf = *(const bf16x8*)&kr[kk * 32];
                sf[fb] = __builtin_amdgcn_mfma_f32_16x16x32_bf16(qa[kk], bf, sf[fb], 0, 0, 0);
            }
        }
        // extra frag: half0 -> cols i=s (first4 + prev q<12); half1 -> i=16+s (prev q>=12)
        int i = half * 16 + s;
        int keyrow = (i < 4) ? i : (qw + (i - 4) - 1);
        if (keyrow < 0) keyrow = 0;
        if (keyrow > 2047) keyrow = 2047;
        const u16* kr = kb + (size_t)keyrow * 512 + kvh * 128 + g * 8;
#pragma unroll
        for (int kk = 0; kk < 4; ++kk) {
            bf16x8 bf = *(const bf16x8*)&kr[kk * 32];
            sf[8] = __builtin_amdgcn_mfma_f32_16x16x32_bf16(qa[kk], bf, sf[8], 0, 0, 0);
        }
    }

    // ---- mask + scale + partial row max ----
    const float scale = 0.08838834764831845f;  // 1/sqrt(128)
    float mx[4] = {-1e30f, -1e30f, -1e30f, -1e30f};
#pragma unroll
    for (int fi = 0; fi < 9; ++fi)
#pragma unroll
        for (int r = 0; r < 4; ++r) {
            int q = g * 4 + r;
            int t = qw + q;
            bool ok;
            if (fi < 8) {
                int j = half * 128 + fi * 16 + s;
                ok = j < (t >> 3);
            } else {
                int i = half * 16 + s;
                if (i < 4) ok = (i <= t);
                else       ok = ((i - 4) == q) && ((t & 7) != 0) && (t >= 5);
            }
            float v = ok ? sf[fi][r] * scale : -1e30f;
            sf[fi][r] = v;
            mx[r] = fmaxf(mx[r], v);
        }
#pragma unroll
    for (int r = 0; r < 4; ++r)
#pragma unroll
        for (int off = 8; off; off >>= 1) mx[r] = fmaxf(mx[r], __shfl_xor(mx[r], off));

    // ---- exp + partial row sum ----
    float sm[4] = {0.f, 0.f, 0.f, 0.f};
#pragma unroll
    for (int fi = 0; fi < 9; ++fi)
#pragma unroll
        for (int r = 0; r < 4; ++r) {
            float p = __expf(sf[fi][r] - mx[r]);
            sf[fi][r] = p;
            sm[r] += p;
        }
#pragma unroll
    for (int r = 0; r < 4; ++r)
#pragma unroll
        for (int off = 8; off; off >>= 1) sm[r] += __shfl_xor(sm[r], off);

    // ---- write P (wave-private): boundary bf16 swizzled, extras f32, m/s ----
#pragma unroll
    for (int fi = 0; fi < 8; ++fi)
#pragma unroll
        for (int r = 0; r < 4; ++r) {
            int q = g * 4 + r;
            int c = fi * 16 + s;            // 0..127
            int blk = (c >> 3) ^ q;         // 0..15
            p_main[w][q * 128 + (blk << 3) + (c & 7)] = f2b(sf[fi][r]);
        }
#pragma unroll
    for (int r = 0; r < 4; ++r) {
        int q = g * 4 + r;
        p_ext[w][q][s] = sf[8][r];
        if (s == q) { p_ms[w][q][0] = mx[r]; p_ms[w][q][1] = sm[r]; }
    }

    // ---- partial PV (this half's 128 keys) via MFMA ----
    bf16x8 pa[4];
#pragma unroll
    for (int kk = 0; kk < 4; ++kk) {
        int blk = (kk * 4 + g) ^ s;
        pa[kk] = *(const bf16x8*)&p_main[w][s * 128 + (blk << 3)];
    }
    f32x4 out[8];
#pragma unroll
    for (int f = 0; f < 8; ++f) out[f] = f32x4{0.f, 0.f, 0.f, 0.f};
    {
        const u16* vtb = vbt + ((size_t)kvh << 15) + half * 128;
#pragma unroll
        for (int f = 0; f < 8; ++f) {
            const u16* vr = vtb + (size_t)(f * 16 + s) * 256 + g * 8;
#pragma unroll
            for (int kk = 0; kk < 4; ++kk) {
                bf16x8 vf = *(const bf16x8*)&vr[kk * 32];
                out[f] = __builtin_amdgcn_mfma_f32_16x16x32_bf16(pa[kk], vf, out[f], 0, 0, 0);
            }
        }
    }

    // ---- extras PV (VALU) ----
    if (half == 0) {
#pragma unroll
        for (int e = 0; e < 4; ++e) {
            float ve[8];
#pragma unroll
            for (int f = 0; f < 8; ++f)
                ve[f] = b2f(vb[(size_t)e * 512 + kvh * 128 + f * 16 + s]);
#pragma unroll
            for (int r = 0; r < 4; ++r) {
                float p = p_ext[w][g * 4 + r][e];
#pragma unroll
                for (int f = 0; f < 8; ++f) out[f][r] += p * ve[f];
            }
        }
#pragma unroll
        for (int r = 0; r < 4; ++r) {
            int q = g * 4 + r;
            if (q < 12) {
                int t = qw + q;
                float pp = p_ext[w][q][4 + q];
                int key = t - 1; if (key < 0) key = 0;
                const u16* vr = vb + (size_t)key * 512 + kvh * 128;
#pragma unroll
                for (int f = 0; f < 8; ++f) out[f][r] += pp * b2f(vr[f * 16 + s]);
            }
        }
    } else {
#pragma unroll
        for (int r = 0; r < 4; ++r) {
            int q = g * 4 + r;
            if (q >= 12) {
                int t = qw + q;
                float pp = p_ext[w][q][q - 12];
                int key = t - 1;
                const u16* vr = vb + (size_t)key * 512 + kvh * 128;
#pragma unroll
                for (int f = 0; f < 8; ++f) out[f][r] += pp * b2f(vr[f * 16 + s]);
            }
        }
    }

    // ---- merge halves (flash combine) ----
    __syncthreads();
    float* mb = (float*)p_main;           // 8192 floats; region qg = [qg*2048, +2048)
    if (half == 1) {
#pragma unroll
        for (int f = 0; f < 8; ++f)
#pragma unroll
            for (int r = 0; r < 4; ++r) {
                int q = g * 4 + r, d = f * 16 + s;
                mb[qg * 2048 + q * 128 + (((d >> 2) ^ (q & 7)) << 2) + (d & 3)] = out[f][r];
            }
    }
    __syncthreads();
    if (half == 0) {
        float f0[4], f1v[4], invS[4];
#pragma unroll
        for (int r = 0; r < 4; ++r) {
            int q = g * 4 + r;
            float m1 = p_ms[2 * qg + 1][q][0];
            float s1 = p_ms[2 * qg + 1][q][1];
            float M  = fmaxf(mx[r], m1);
            f0[r]  = __expf(mx[r] - M);
            f1v[r] = __expf(m1 - M);
            invS[r] = 1.f / (f0[r] * sm[r] + f1v[r] * s1);
        }
#pragma unroll
        for (int f = 0; f < 8; ++f)
#pragma unroll
            for (int r = 0; r < 4; ++r) {
                int q = g * 4 + r, d = f * 16 + s;
                int t = qw + q;
                float o1 = mb[qg * 2048 + q * 128 + (((d >> 2) ^ (q & 7)) << 2) + (d & 3)];
                float val = (f0[r] * out[f][r] + f1v[r] * o1) * invS[r];
                aout[(size_t)t * 2048 + h * 128 + d] = f2b(val);
            }
    }
}

// ---------------------------------------------------------------------------
extern "C" void kernel_launch(void* const* d_in, const int* in_sizes, int n_in,
                              void* d_out, int out_size, void* d_ws, size_t ws_size,
                              hipStream_t stream) {
    const float* x   = (const float*)d_in[0];
    const float* fc  = (const float*)d_in[1];
    const float* wq  = (const float*)d_in[2];
    const float* wk  = (const float*)d_in[3];
    const float* wv  = (const float*)d_in[4];
    const float* wo  = (const float*)d_in[5];
    const float* alk = (const float*)d_in[6];
    const float* bk  = (const float*)d_in[7];
    const float* ck  = (const float*)d_in[8];
    const float* alv = (const float*)d_in[9];
    const float* bv  = (const float*)d_in[10];
    const float* cv  = (const float*)d_in[11];

    char* ws = (char*)d_ws;
    u16*   xb   = (u16*)(ws);                  //  8,388,608 B
    u16*   wcat = (u16*)(ws + 8388608);        // 12,582,912 B
    u16*   wob  = (u16*)(ws + 20971520);       //  8,388,608 B
    float* c1   = (float*)(ws + 29360128);     // 25,165,824 B
    u16*   qb   = (u16*)(ws + 54525952);       //  8,388,608 B
    u16*   kb   = (u16*)(ws + 62914560);       //  2,097,152 B
    u16*   vb   = (u16*)(ws + 65011712);       //  2,097,152 B
    u16*   kbc  = (u16*)(ws + 67108864);       //    262,144 B
    u16*   vbt  = (u16*)(ws + 67371008);       //    262,144 B
    u16*   aout = (u16*)(ws + 67633152);       //  8,388,608 B

    convert_kernel<<<14336, 256, 0, stream>>>(x, wq, wk, wv, wo, xb, wcat, wob);

    dim3 g1(3072 / 128, 2048 / 128);
    gemm_bt_kernel<<<g1, 512, 0, stream>>>(xb, wcat, c1, 2048, 3072, 2048);

    ssm_rope_kernel<<<8960, 256, 0, stream>>>(c1, fc, alk, bk, ck, alv, bv, cv, qb, kb, vb);

    compact_kernel<<<512, 256, 0, stream>>>(kb, vb, kbc, vbt);

    attn_kernel<<<512, 512, 0, stream>>>(qb, kb, vb, kbc, vbt, aout);

    dim3 g3(2048 / 128, 2048 / 128);
    gemm_bt_kernel<<<g3, 512, 0, stream>>>(aout, wob, (float*)d_out, 2048, 2048, 2048);
}

// Round 5
// 117.994 us; speedup vs baseline: 1.2093x; 1.2093x over previous
//
#include <hip/hip_runtime.h>

typedef __bf16 bf16x8 __attribute__((ext_vector_type(8)));
typedef float  f32x4  __attribute__((ext_vector_type(4)));
typedef unsigned short u16;
typedef unsigned int   u32;

__device__ __forceinline__ float b2f(u16 u) {
    u32 x = ((u32)u) << 16;
    return __builtin_bit_cast(float, x);
}
__device__ __forceinline__ u16 f2b(float f) {
    u32 x = __builtin_bit_cast(u32, f);
    x += 0x7fffu + ((x >> 16) & 1u);   // RNE
    return (u16)(x >> 16);
}

// ---------------------------------------------------------------------------
// Kernel 1: convert x, [wq;wk;wv], wo  f32 -> bf16  (vectorized x4)
// ---------------------------------------------------------------------------
__global__ void convert_kernel(const float* __restrict__ x, const float* __restrict__ wq,
                               const float* __restrict__ wk, const float* __restrict__ wv,
                               const float* __restrict__ wo,
                               u16* __restrict__ xb, u16* __restrict__ wcat, u16* __restrict__ wob)
{
    long i4 = (long)blockIdx.x * 256 + threadIdx.x;   // 0..3670015
    long e = i4 * 4;
    const float* src; u16* dst;
    if (e < 4194304) { src = x + e; dst = xb + e; }
    else if (e < 10485760) {
        long j = e - 4194304;
        dst = wcat + j;
        if (j < 4194304)      src = wq + j;
        else if (j < 5242880) src = wk + (j - 4194304);
        else                  src = wv + (j - 5242880);
    } else {
        long j = e - 10485760;
        src = wo + j; dst = wob + j;
    }
    float4 v = *(const float4*)src;
    uint2 pk;
    pk.x = (u32)f2b(v.x) | ((u32)f2b(v.y) << 16);
    pk.y = (u32)f2b(v.z) | ((u32)f2b(v.w) << 16);
    *(uint2*)dst = pk;
}

// ---------------------------------------------------------------------------
// Kernel 2: bf16 GEMM  C[M][N] f32 = A[M][K] * B[N][K]^T
// 128x128 tile, BK=64, 512 threads = 8 waves (2M x 4N), wave = 64x32 out.
// ---------------------------------------------------------------------------
__global__ __launch_bounds__(512) void gemm_bt_kernel(
    const u16* __restrict__ A, const u16* __restrict__ B,
    float* __restrict__ C, int M, int N, int K)
{
    __shared__ u16 As[128 * 64];
    __shared__ u16 Bs[128 * 64];
    const int tid  = threadIdx.x;
    const int lane = tid & 63;
    const int wave = tid >> 6;
    const int waveM = wave >> 2, waveN = wave & 3;
    const int tm = blockIdx.y * 128;
    const int tn = blockIdx.x * 128;

    f32x4 acc[4][2];
#pragma unroll
    for (int i = 0; i < 4; ++i)
#pragma unroll
        for (int j = 0; j < 2; ++j) acc[i][j] = f32x4{0.f, 0.f, 0.f, 0.f};

    const int frow = lane & 15;
    const int fk   = (lane >> 4) * 8;

    for (int kt = 0; kt < K; kt += 64) {
#pragma unroll
        for (int c = 0; c < 2; ++c) {
            int idx = c * 512 + tid;
            int row = idx >> 3;
            int blk = (idx & 7) ^ (row & 7);
            const u16* srcA = A + (size_t)(tm + row) * K + kt + blk * 8;
            const u16* srcB = B + (size_t)(tn + row) * K + kt + blk * 8;
            u16* dstA = As + (size_t)(c * 512 + wave * 64) * 8;
            u16* dstB = Bs + (size_t)(c * 512 + wave * 64) * 8;
            __builtin_amdgcn_global_load_lds((const __attribute__((address_space(1))) void*)srcA,
                                             (__attribute__((address_space(3))) void*)dstA, 16, 0, 0);
            __builtin_amdgcn_global_load_lds((const __attribute__((address_space(1))) void*)srcB,
                                             (__attribute__((address_space(3))) void*)dstB, 16, 0, 0);
        }
        __syncthreads();
#pragma unroll
        for (int kk = 0; kk < 64; kk += 32) {
            bf16x8 af[4], bfr[2];
#pragma unroll
            for (int m = 0; m < 4; ++m) {
                int r  = waveM * 64 + m * 16 + frow;
                int kb_ = ((kk + fk) >> 3) ^ (r & 7);
                af[m] = *(const bf16x8*)&As[r * 64 + kb_ * 8];
            }
#pragma unroll
            for (int n = 0; n < 2; ++n) {
                int r  = waveN * 32 + n * 16 + frow;
                int kb_ = ((kk + fk) >> 3) ^ (r & 7);
                bfr[n] = *(const bf16x8*)&Bs[r * 64 + kb_ * 8];
            }
#pragma unroll
            for (int m = 0; m < 4; ++m)
#pragma unroll
                for (int n = 0; n < 2; ++n)
                    acc[m][n] = __builtin_amdgcn_mfma_f32_16x16x32_bf16(af[m], bfr[n], acc[m][n], 0, 0, 0);
        }
        __syncthreads();
    }
    const int rb = tm + waveM * 64;
    const int cb = tn + waveN * 32;
#pragma unroll
    for (int m = 0; m < 4; ++m)
#pragma unroll
        for (int n = 0; n < 2; ++n)
#pragma unroll
            for (int r = 0; r < 4; ++r) {
                int row = rb + m * 16 + (lane >> 4) * 4 + r;
                int col = cb + n * 16 + (lane & 15);
                C[(size_t)row * N + col] = acc[m][n][r];
            }
}

// ---------------------------------------------------------------------------
// Kernel 3: SSM + residual + RoPE (unchanged)
// ---------------------------------------------------------------------------
__global__ void ssm_rope_kernel(const float* __restrict__ c1, const float* __restrict__ fc,
                                const float* __restrict__ alk, const float* __restrict__ bk,
                                const float* __restrict__ ck,
                                const float* __restrict__ alv, const float* __restrict__ bv,
                                const float* __restrict__ cv,
                                u16* __restrict__ qb, u16* __restrict__ kb, u16* __restrict__ vb)
{
    int gi = blockIdx.x * 256 + threadIdx.x;
    if (gi < 2097152) {
        int s = gi >> 10, pg = gi & 1023;
        int i = pg & 63;
        int e0 = (pg >> 6) * 128 + 2 * i;
        float2 xv = *(const float2*)&c1[(size_t)s * 3072 + e0];
        float4 f = *(const float4*)&fc[((size_t)s * 64 + i) * 4];
        float q0 = xv.x * f.x - xv.y * f.z;
        float q1 = xv.x * f.z + xv.y * f.x;
        *(u32*)&qb[(size_t)s * 2048 + e0] = (u32)f2b(q0) | ((u32)f2b(q1) << 16);
    } else if (gi < 2097152 + 65536) {
        int ki = gi - 2097152;
        int chunk = ki >> 8, pr = ki & 255;
        int i = pr & 63;
        int e0 = (pr >> 6) * 128 + 2 * i;
        float z0 = alk[e0], z1 = alk[e0 + 1];
        float sp0 = z0 > 20.f ? z0 : log1pf(__expf(z0));
        float sp1 = z1 > 20.f ? z1 : log1pf(__expf(z1));
        float a0 = __expf(-sp0), a1 = __expf(-sp1);
        float b0 = bk[e0], b1 = bk[e0 + 1];
        float c0 = ck[e0], cc1 = ck[e0 + 1];
        float h0 = 0.f, h1 = 0.f;
#pragma unroll
        for (int tt = 0; tt < 8; ++tt) {
            int s = chunk * 8 + tt;
            float2 xv = *(const float2*)&c1[(size_t)s * 3072 + 2048 + e0];
            h0 = a0 * h0 + b0 * xv.x;
            h1 = a1 * h1 + b1 * xv.y;
            float y0 = c0 * h0 + xv.x;
            float y1 = cc1 * h1 + xv.y;
            float4 f = *(const float4*)&fc[((size_t)s * 64 + i) * 4];
            float k0 = y0 * f.x - y1 * f.z;
            float k1 = y0 * f.z + y1 * f.x;
            *(u32*)&kb[(size_t)s * 512 + e0] = (u32)f2b(k0) | ((u32)f2b(k1) << 16);
        }
    } else {
        int vi = gi - 2097152 - 65536;
        int chunk = vi >> 9, e = vi & 511;
        float z = alv[e];
        float sp = z > 20.f ? z : log1pf(__expf(z));
        float a = __expf(-sp);
        float b = bv[e], c = cv[e];
        float h = 0.f;
#pragma unroll
        for (int tt = 0; tt < 8; ++tt) {
            int s = chunk * 8 + tt;
            float xvv = c1[(size_t)s * 3072 + 2560 + e];
            h = a * h + b * xvv;
            vb[(size_t)s * 512 + e] = f2b(c * h + xvv);
        }
    }
}

// ---------------------------------------------------------------------------
// Kernel 4: compact boundary keys (pos = 8j+7, j<256):
//   kbc[kvh][j][d]  row-major K rows  (QK^T B-operand)
//   vbt[kvh][d][j]  transposed V      (PV    B-operand)
// ---------------------------------------------------------------------------
__global__ void compact_kernel(const u16* __restrict__ kb, const u16* __restrict__ vb,
                               u16* __restrict__ kbc, u16* __restrict__ vbt)
{
    int id = blockIdx.x * 256 + threadIdx.x;    // 131072
    int kvh = id >> 15, rem = id & 32767, j = rem >> 7, d = rem & 127;
    int src = (8 * j + 7) * 512 + kvh * 128 + d;
    kbc[(((kvh << 8) + j) << 7) + d] = kb[src];
    vbt[(((kvh << 7) + d) << 8) + j] = vb[src];
}

// ---------------------------------------------------------------------------
// Kernel 5: MFMA sparse attention, LDS-resident K/V.
// Block = (head, 128 queries) -> 256 blocks (1/CU). 8 waves x 16 queries,
// each wave does all 256 boundary keys + 2 extra frags.
// Stage K (64KB, swizzled) -> QK from LDS; V^T staged during QK; K buffer
// reused as P buffer for PV. No cross-wave merge.
// ---------------------------------------------------------------------------
__global__ __launch_bounds__(512, 2) void attn_kernel(
    const u16* __restrict__ qb, const u16* __restrict__ kb, const u16* __restrict__ vb,
    const u16* __restrict__ kbc, const u16* __restrict__ vbt, u16* __restrict__ aout)
{
    __shared__ u16   ksbuf[32768];        // 64KB: K tile, then P buffer
    __shared__ u16   vsbuf[32768];        // 64KB: V^T tile
    __shared__ float p_ext[8][16][32];    // 16KB: extra-col P

    const int tid  = threadIdx.x;
    const int w    = tid >> 6;
    const int lane = tid & 63;
    const int s    = lane & 15;     // frag col / A-row
    const int g    = lane >> 4;     // k-group
    const int h    = blockIdx.x >> 4;
    const int t0   = (blockIdx.x & 15) * 128;
    const int kvh  = h >> 2;
    const int qw   = t0 + w * 16;   // wave's first query

    // ---- stage K: 256 rows x 256B, 16 chunks/row, swizzled source ----
    {
        const u16* kcb = kbc + ((size_t)kvh << 15);
#pragma unroll
        for (int it = 0; it < 8; ++it) {
            int idx = it * 512 + tid;
            int r = idx >> 4, b = idx & 15;
            const u16* src = kcb + r * 128 + ((b ^ (r & 7)) << 3);
            u16* dst = ksbuf + (size_t)(it * 512 + w * 64) * 8;
            __builtin_amdgcn_global_load_lds((const __attribute__((address_space(1))) void*)src,
                                             (__attribute__((address_space(3))) void*)dst, 16, 0, 0);
        }
    }
    __syncthreads();

    // ---- issue V^T staging now; latency hides under QK ----
    {
        const u16* vtb = vbt + ((size_t)kvh << 15);
#pragma unroll
        for (int it = 0; it < 8; ++it) {
            int idx = it * 512 + tid;
            int r = idx >> 5, b = idx & 31;
            const u16* src = vtb + r * 256 + ((b ^ (r & 7)) << 3);
            u16* dst = vsbuf + (size_t)(it * 512 + w * 64) * 8;
            __builtin_amdgcn_global_load_lds((const __attribute__((address_space(1))) void*)src,
                                             (__attribute__((address_space(3))) void*)dst, 16, 0, 0);
        }
    }

    // ---- Q A-fragments ----
    bf16x8 qa[4];
    {
        const u16* qr = qb + (size_t)(qw + s) * 2048 + h * 128 + g * 8;
#pragma unroll
        for (int kk = 0; kk < 4; ++kk) qa[kk] = *(const bf16x8*)&qr[kk * 32];
    }

    // ---- scores: 16 boundary frags (LDS) + 2 extra frags (L2) ----
    f32x4 sf[18];
#pragma unroll
    for (int i = 0; i < 18; ++i) sf[i] = f32x4{0.f, 0.f, 0.f, 0.f};

#pragma unroll
    for (int fb = 0; fb < 16; ++fb) {
        int row = fb * 16 + s;
#pragma unroll
        for (int kk = 0; kk < 4; ++kk) {
            int ch = (kk * 4 + g) ^ (s & 7);
            bf16x8 bf = *(const bf16x8*)&ksbuf[row * 128 + ch * 8];
            sf[fb] = __builtin_amdgcn_mfma_f32_16x16x32_bf16(qa[kk], bf, sf[fb], 0, 0, 0);
        }
    }
#pragma unroll
    for (int xb = 0; xb < 2; ++xb) {
        int i = xb * 16 + s;
        int keyrow = (i < 4) ? i : (qw + (i - 4) - 1);
        if (keyrow < 0) keyrow = 0;
        if (keyrow > 2047) keyrow = 2047;
        const u16* kr = kb + (size_t)keyrow * 512 + kvh * 128 + g * 8;
#pragma unroll
        for (int kk = 0; kk < 4; ++kk) {
            bf16x8 bf = *(const bf16x8*)&kr[kk * 32];
            sf[16 + xb] = __builtin_amdgcn_mfma_f32_16x16x32_bf16(qa[kk], bf, sf[16 + xb], 0, 0, 0);
        }
    }

    // ---- mask + scale + row max ----
    const float scale = 0.08838834764831845f;  // 1/sqrt(128)
    float mx[4] = {-1e30f, -1e30f, -1e30f, -1e30f};
#pragma unroll
    for (int fi = 0; fi < 18; ++fi)
#pragma unroll
        for (int r = 0; r < 4; ++r) {
            int q = g * 4 + r;
            int t = qw + q;
            bool ok;
            if (fi < 16) {
                int j = fi * 16 + s;
                ok = j < (t >> 3);
            } else {
                int i = (fi - 16) * 16 + s;
                if (i < 4) ok = (i <= t);
                else       ok = ((i - 4) == q) && ((t & 7) != 0) && (t >= 5);
            }
            float v = ok ? sf[fi][r] * scale : -1e30f;
            sf[fi][r] = v;
            mx[r] = fmaxf(mx[r], v);
        }
#pragma unroll
    for (int r = 0; r < 4; ++r)
#pragma unroll
        for (int off = 8; off; off >>= 1) mx[r] = fmaxf(mx[r], __shfl_xor(mx[r], off));

    // ---- exp + row sum ----
    float sm[4] = {0.f, 0.f, 0.f, 0.f};
#pragma unroll
    for (int fi = 0; fi < 18; ++fi)
#pragma unroll
        for (int r = 0; r < 4; ++r) {
            float p = __expf(sf[fi][r] - mx[r]);
            sf[fi][r] = p;
            sm[r] += p;
        }
#pragma unroll
    for (int r = 0; r < 4; ++r)
#pragma unroll
        for (int off = 8; off; off >>= 1) sm[r] += __shfl_xor(sm[r], off);
    float inv[4];
#pragma unroll
    for (int r = 0; r < 4; ++r) inv[r] = 1.f / sm[r];

    // ---- all waves done reading K; V staged (barrier drains vmcnt) ----
    __syncthreads();

    // ---- write P: main (bf16, swizzled) into ksbuf region, extras f32 ----
    u16* pbuf = ksbuf + w * 4096;
#pragma unroll
    for (int fi = 0; fi < 16; ++fi)
#pragma unroll
        for (int r = 0; r < 4; ++r) {
            int q = g * 4 + r;
            int c = fi * 16 + s;
            int blk = (c >> 3) ^ q;
            pbuf[q * 256 + (blk << 3) + (c & 7)] = f2b(sf[fi][r]);
        }
#pragma unroll
    for (int xb = 0; xb < 2; ++xb)
#pragma unroll
        for (int r = 0; r < 4; ++r)
            p_ext[w][g * 4 + r][xb * 16 + s] = sf[16 + xb][r];

    // ---- PV main: out[16q][128d] via MFMA, P and V^T both in LDS ----
    bf16x8 pa[8];
#pragma unroll
    for (int kk = 0; kk < 8; ++kk) {
        int blk = (kk * 4 + g) ^ s;
        pa[kk] = *(const bf16x8*)&pbuf[s * 256 + (blk << 3)];
    }
    f32x4 out[8];
#pragma unroll
    for (int f = 0; f < 8; ++f) out[f] = f32x4{0.f, 0.f, 0.f, 0.f};
#pragma unroll
    for (int f = 0; f < 8; ++f) {
        int row = f * 16 + s;
#pragma unroll
        for (int kk = 0; kk < 8; ++kk) {
            int ch = (kk * 4 + g) ^ (s & 7);
            bf16x8 vf = *(const bf16x8*)&vsbuf[row * 256 + ch * 8];
            out[f] = __builtin_amdgcn_mfma_f32_16x16x32_bf16(pa[kk], vf, out[f], 0, 0, 0);
        }
    }

    // ---- PV extras (VALU): first-4 keys + per-query prev key ----
    {
        float v4[4][8];
#pragma unroll
        for (int e = 0; e < 4; ++e)
#pragma unroll
            for (int f = 0; f < 8; ++f)
                v4[e][f] = b2f(vb[(size_t)e * 512 + kvh * 128 + f * 16 + s]);
#pragma unroll
        for (int r = 0; r < 4; ++r) {
            int q = g * 4 + r;
            int t = qw + q;
#pragma unroll
            for (int e = 0; e < 4; ++e) {
                float p = p_ext[w][q][e];
#pragma unroll
                for (int f = 0; f < 8; ++f) out[f][r] += p * v4[e][f];
            }
            float pp = p_ext[w][q][4 + q];
            int key = t - 1; if (key < 0) key = 0;
            const u16* vr = vb + (size_t)key * 512 + kvh * 128;
#pragma unroll
            for (int f = 0; f < 8; ++f) out[f][r] += pp * b2f(vr[f * 16 + s]);
        }
    }

    // ---- normalize + store ----
#pragma unroll
    for (int f = 0; f < 8; ++f)
#pragma unroll
        for (int r = 0; r < 4; ++r) {
            int t = qw + g * 4 + r;
            aout[(size_t)t * 2048 + h * 128 + f * 16 + s] = f2b(out[f][r] * inv[r]);
        }
}

// ---------------------------------------------------------------------------
extern "C" void kernel_launch(void* const* d_in, const int* in_sizes, int n_in,
                              void* d_out, int out_size, void* d_ws, size_t ws_size,
                              hipStream_t stream) {
    const float* x   = (const float*)d_in[0];
    const float* fc  = (const float*)d_in[1];
    const float* wq  = (const float*)d_in[2];
    const float* wk  = (const float*)d_in[3];
    const float* wv  = (const float*)d_in[4];
    const float* wo  = (const float*)d_in[5];
    const float* alk = (const float*)d_in[6];
    const float* bk  = (const float*)d_in[7];
    const float* ck  = (const float*)d_in[8];
    const float* alv = (const float*)d_in[9];
    const float* bv  = (const float*)d_in[10];
    const float* cv  = (const float*)d_in[11];

    char* ws = (char*)d_ws;
    u16*   xb   = (u16*)(ws);                  //  8,388,608 B
    u16*   wcat = (u16*)(ws + 8388608);        // 12,582,912 B
    u16*   wob  = (u16*)(ws + 20971520);       //  8,388,608 B
    float* c1   = (float*)(ws + 29360128);     // 25,165,824 B
    u16*   qb   = (u16*)(ws + 54525952);       //  8,388,608 B
    u16*   kb   = (u16*)(ws + 62914560);       //  2,097,152 B
    u16*   vb   = (u16*)(ws + 65011712);       //  2,097,152 B
    u16*   kbc  = (u16*)(ws + 67108864);       //    262,144 B
    u16*   vbt  = (u16*)(ws + 67371008);       //    262,144 B
    u16*   aout = (u16*)(ws + 67633152);       //  8,388,608 B

    convert_kernel<<<14336, 256, 0, stream>>>(x, wq, wk, wv, wo, xb, wcat, wob);

    dim3 g1(3072 / 128, 2048 / 128);
    gemm_bt_kernel<<<g1, 512, 0, stream>>>(xb, wcat, c1, 2048, 3072, 2048);

    ssm_rope_kernel<<<8960, 256, 0, stream>>>(c1, fc, alk, bk, ck, alv, bv, cv, qb, kb, vb);

    compact_kernel<<<512, 256, 0, stream>>>(kb, vb, kbc, vbt);

    attn_kernel<<<256, 512, 0, stream>>>(qb, kb, vb, kbc, vbt, aout);

    dim3 g3(2048 / 128, 2048 / 128);
    gemm_bt_kernel<<<g3, 512, 0, stream>>>(aout, wob, (float*)d_out, 2048, 2048, 2048);
}

// Round 6
// 116.319 us; speedup vs baseline: 1.2267x; 1.0144x over previous
//
#include <hip/hip_runtime.h>

typedef __bf16 bf16x8 __attribute__((ext_vector_type(8)));
typedef float  f32x4  __attribute__((ext_vector_type(4)));
typedef unsigned short u16;
typedef unsigned int   u32;

__device__ __forceinline__ float b2f(u16 u) {
    u32 x = ((u32)u) << 16;
    return __builtin_bit_cast(float, x);
}
__device__ __forceinline__ u16 f2b(float f) {
    u32 x = __builtin_bit_cast(u32, f);
    x += 0x7fffu + ((x >> 16) & 1u);   // RNE
    return (u16)(x >> 16);
}

// ---------------------------------------------------------------------------
// Kernel 1: convert x, [wq;wk;wv], wo  f32 -> bf16  (vectorized x4)
// ---------------------------------------------------------------------------
__global__ void convert_kernel(const float* __restrict__ x, const float* __restrict__ wq,
                               const float* __restrict__ wk, const float* __restrict__ wv,
                               const float* __restrict__ wo,
                               u16* __restrict__ xb, u16* __restrict__ wcat, u16* __restrict__ wob)
{
    long i4 = (long)blockIdx.x * 256 + threadIdx.x;   // 0..3670015
    long e = i4 * 4;
    const float* src; u16* dst;
    if (e < 4194304) { src = x + e; dst = xb + e; }
    else if (e < 10485760) {
        long j = e - 4194304;
        dst = wcat + j;
        if (j < 4194304)      src = wq + j;
        else if (j < 5242880) src = wk + (j - 4194304);
        else                  src = wv + (j - 5242880);
    } else {
        long j = e - 10485760;
        src = wo + j; dst = wob + j;
    }
    float4 v = *(const float4*)src;
    uint2 pk;
    pk.x = (u32)f2b(v.x) | ((u32)f2b(v.y) << 16);
    pk.y = (u32)f2b(v.z) | ((u32)f2b(v.w) << 16);
    *(uint2*)dst = pk;
}

// ---------------------------------------------------------------------------
// Kernel 2: bf16 GEMM  C[M][N] = A[M][K] * B[N][K]^T, output f32 or bf16.
// 128x128 tile, BK=64, 512 threads = 8 waves (2M x 4N), wave = 64x32 out.
// 2-phase double-buffered K-loop (T3-min): STAGE(next) issued before
// compute(cur); one __syncthreads (vmcnt0+lgkmcnt0) per K-step.
// ---------------------------------------------------------------------------
template<int OUT_BF16>
__global__ __launch_bounds__(512) void gemm_bt_kernel(
    const u16* __restrict__ A, const u16* __restrict__ B,
    void* __restrict__ Cout, int M, int N, int K)
{
    __shared__ u16 As[2][8192];
    __shared__ u16 Bs[2][8192];
    const int tid  = threadIdx.x;
    const int lane = tid & 63;
    const int wave = tid >> 6;
    const int waveM = wave >> 2, waveN = wave & 3;
    const int tm = blockIdx.y * 128;
    const int tn = blockIdx.x * 128;

    f32x4 acc[4][2];
#pragma unroll
    for (int i = 0; i < 4; ++i)
#pragma unroll
        for (int j = 0; j < 2; ++j) acc[i][j] = f32x4{0.f, 0.f, 0.f, 0.f};

    const int frow = lane & 15;
    const int fk   = (lane >> 4) * 8;

    auto STAGE = [&](int buf, int kt) {
#pragma unroll
        for (int c = 0; c < 2; ++c) {
            int idx = c * 512 + tid;            // 16B-chunk index, 0..1023
            int row = idx >> 3;                 // tile row
            int blk = (idx & 7) ^ (row & 7);    // swizzled source 16B block
            const u16* srcA = A + (size_t)(tm + row) * K + kt + blk * 8;
            const u16* srcB = B + (size_t)(tn + row) * K + kt + blk * 8;
            u16* dstA = &As[buf][(size_t)(c * 512 + wave * 64) * 8];
            u16* dstB = &Bs[buf][(size_t)(c * 512 + wave * 64) * 8];
            __builtin_amdgcn_global_load_lds((const __attribute__((address_space(1))) void*)srcA,
                                             (__attribute__((address_space(3))) void*)dstA, 16, 0, 0);
            __builtin_amdgcn_global_load_lds((const __attribute__((address_space(1))) void*)srcB,
                                             (__attribute__((address_space(3))) void*)dstB, 16, 0, 0);
        }
    };
    auto COMPUTE = [&](int buf) {
#pragma unroll
        for (int kk = 0; kk < 64; kk += 32) {
            bf16x8 af[4], bfr[2];
#pragma unroll
            for (int m = 0; m < 4; ++m) {
                int r  = waveM * 64 + m * 16 + frow;
                int kb_ = ((kk + fk) >> 3) ^ (r & 7);
                af[m] = *(const bf16x8*)&As[buf][r * 64 + kb_ * 8];
            }
#pragma unroll
            for (int n = 0; n < 2; ++n) {
                int r  = waveN * 32 + n * 16 + frow;
                int kb_ = ((kk + fk) >> 3) ^ (r & 7);
                bfr[n] = *(const bf16x8*)&Bs[buf][r * 64 + kb_ * 8];
            }
#pragma unroll
            for (int m = 0; m < 4; ++m)
#pragma unroll
                for (int n = 0; n < 2; ++n)
                    acc[m][n] = __builtin_amdgcn_mfma_f32_16x16x32_bf16(af[m], bfr[n], acc[m][n], 0, 0, 0);
        }
    };

    // prologue
    STAGE(0, 0);
    __syncthreads();
    int cur = 0;
    for (int kt = 64; kt < K; kt += 64) {
        STAGE(cur ^ 1, kt);       // next tile's loads fly during compute
        COMPUTE(cur);
        __syncthreads();          // vmcnt(0)+lgkmcnt(0): next buf ready, cur free
        cur ^= 1;
    }
    COMPUTE(cur);

    const int rb = tm + waveM * 64;
    const int cb = tn + waveN * 32;
#pragma unroll
    for (int m = 0; m < 4; ++m)
#pragma unroll
        for (int n = 0; n < 2; ++n)
#pragma unroll
            for (int r = 0; r < 4; ++r) {
                int row = rb + m * 16 + (lane >> 4) * 4 + r;
                int col = cb + n * 16 + (lane & 15);
                if (OUT_BF16) ((u16*)Cout)[(size_t)row * N + col] = f2b(acc[m][n][r]);
                else          ((float*)Cout)[(size_t)row * N + col] = acc[m][n][r];
            }
}

// ---------------------------------------------------------------------------
// Kernel 3: SSM + residual + RoPE.  c1 is now bf16.
// ---------------------------------------------------------------------------
__global__ void ssm_rope_kernel(const u16* __restrict__ c1, const float* __restrict__ fc,
                                const float* __restrict__ alk, const float* __restrict__ bk,
                                const float* __restrict__ ck,
                                const float* __restrict__ alv, const float* __restrict__ bv,
                                const float* __restrict__ cv,
                                u16* __restrict__ qb, u16* __restrict__ kb, u16* __restrict__ vb)
{
    int gi = blockIdx.x * 256 + threadIdx.x;
    if (gi < 2097152) {
        int s = gi >> 10, pg = gi & 1023;
        int i = pg & 63;
        int e0 = (pg >> 6) * 128 + 2 * i;
        u32 u = *(const u32*)&c1[(size_t)s * 3072 + e0];
        float x0 = b2f((u16)(u & 0xffff)), x1 = b2f((u16)(u >> 16));
        float4 f = *(const float4*)&fc[((size_t)s * 64 + i) * 4];
        float q0 = x0 * f.x - x1 * f.z;
        float q1 = x0 * f.z + x1 * f.x;
        *(u32*)&qb[(size_t)s * 2048 + e0] = (u32)f2b(q0) | ((u32)f2b(q1) << 16);
    } else if (gi < 2097152 + 65536) {
        int ki = gi - 2097152;
        int chunk = ki >> 8, pr = ki & 255;
        int i = pr & 63;
        int e0 = (pr >> 6) * 128 + 2 * i;
        float z0 = alk[e0], z1 = alk[e0 + 1];
        float sp0 = z0 > 20.f ? z0 : log1pf(__expf(z0));
        float sp1 = z1 > 20.f ? z1 : log1pf(__expf(z1));
        float a0 = __expf(-sp0), a1 = __expf(-sp1);
        float b0 = bk[e0], b1 = bk[e0 + 1];
        float c0 = ck[e0], cc1 = ck[e0 + 1];
        float h0 = 0.f, h1 = 0.f;
#pragma unroll
        for (int tt = 0; tt < 8; ++tt) {
            int s = chunk * 8 + tt;
            u32 u = *(const u32*)&c1[(size_t)s * 3072 + 2048 + e0];
            float x0 = b2f((u16)(u & 0xffff)), x1 = b2f((u16)(u >> 16));
            h0 = a0 * h0 + b0 * x0;
            h1 = a1 * h1 + b1 * x1;
            float y0 = c0 * h0 + x0;
            float y1 = cc1 * h1 + x1;
            float4 f = *(const float4*)&fc[((size_t)s * 64 + i) * 4];
            float k0 = y0 * f.x - y1 * f.z;
            float k1 = y0 * f.z + y1 * f.x;
            *(u32*)&kb[(size_t)s * 512 + e0] = (u32)f2b(k0) | ((u32)f2b(k1) << 16);
        }
    } else {
        int vi = gi - 2097152 - 65536;
        int chunk = vi >> 9, e = vi & 511;
        float z = alv[e];
        float sp = z > 20.f ? z : log1pf(__expf(z));
        float a = __expf(-sp);
        float b = bv[e], c = cv[e];
        float h = 0.f;
#pragma unroll
        for (int tt = 0; tt < 8; ++tt) {
            int s = chunk * 8 + tt;
            float xvv = b2f(c1[(size_t)s * 3072 + 2560 + e]);
            h = a * h + b * xvv;
            vb[(size_t)s * 512 + e] = f2b(c * h + xvv);
        }
    }
}

// ---------------------------------------------------------------------------
// Kernel 4: compact boundary keys (pos = 8j+7, j<256):
//   kbc[kvh][j][d]  row-major K rows  (QK^T B-operand)
//   vbt[kvh][d][j]  transposed V      (PV    B-operand)
// ---------------------------------------------------------------------------
__global__ void compact_kernel(const u16* __restrict__ kb, const u16* __restrict__ vb,
                               u16* __restrict__ kbc, u16* __restrict__ vbt)
{
    int id = blockIdx.x * 256 + threadIdx.x;    // 131072
    int kvh = id >> 15, rem = id & 32767, j = rem >> 7, d = rem & 127;
    int src = (8 * j + 7) * 512 + kvh * 128 + d;
    kbc[(((kvh << 8) + j) << 7) + d] = kb[src];
    vbt[(((kvh << 7) + d) << 8) + j] = vb[src];
}

// ---------------------------------------------------------------------------
// Kernel 5: MFMA sparse attention, LDS-resident K/V (unchanged from round 5)
// ---------------------------------------------------------------------------
__global__ __launch_bounds__(512, 2) void attn_kernel(
    const u16* __restrict__ qb, const u16* __restrict__ kb, const u16* __restrict__ vb,
    const u16* __restrict__ kbc, const u16* __restrict__ vbt, u16* __restrict__ aout)
{
    __shared__ u16   ksbuf[32768];        // 64KB: K tile, then P buffer
    __shared__ u16   vsbuf[32768];        // 64KB: V^T tile
    __shared__ float p_ext[8][16][32];    // 16KB: extra-col P

    const int tid  = threadIdx.x;
    const int w    = tid >> 6;
    const int lane = tid & 63;
    const int s    = lane & 15;     // frag col / A-row
    const int g    = lane >> 4;     // k-group
    const int h    = blockIdx.x >> 4;
    const int t0   = (blockIdx.x & 15) * 128;
    const int kvh  = h >> 2;
    const int qw   = t0 + w * 16;   // wave's first query

    {
        const u16* kcb = kbc + ((size_t)kvh << 15);
#pragma unroll
        for (int it = 0; it < 8; ++it) {
            int idx = it * 512 + tid;
            int r = idx >> 4, b = idx & 15;
            const u16* src = kcb + r * 128 + ((b ^ (r & 7)) << 3);
            u16* dst = ksbuf + (size_t)(it * 512 + w * 64) * 8;
            __builtin_amdgcn_global_load_lds((const __attribute__((address_space(1))) void*)src,
                                             (__attribute__((address_space(3))) void*)dst, 16, 0, 0);
        }
    }
    __syncthreads();

    {
        const u16* vtb = vbt + ((size_t)kvh << 15);
#pragma unroll
        for (int it = 0; it < 8; ++it) {
            int idx = it * 512 + tid;
            int r = idx >> 5, b = idx & 31;
            const u16* src = vtb + r * 256 + ((b ^ (r & 7)) << 3);
            u16* dst = vsbuf + (size_t)(it * 512 + w * 64) * 8;
            __builtin_amdgcn_global_load_lds((const __attribute__((address_space(1))) void*)src,
                                             (__attribute__((address_space(3))) void*)dst, 16, 0, 0);
        }
    }

    bf16x8 qa[4];
    {
        const u16* qr = qb + (size_t)(qw + s) * 2048 + h * 128 + g * 8;
#pragma unroll
        for (int kk = 0; kk < 4; ++kk) qa[kk] = *(const bf16x8*)&qr[kk * 32];
    }

    f32x4 sf[18];
#pragma unroll
    for (int i = 0; i < 18; ++i) sf[i] = f32x4{0.f, 0.f, 0.f, 0.f};

#pragma unroll
    for (int fb = 0; fb < 16; ++fb) {
        int row = fb * 16 + s;
#pragma unroll
        for (int kk = 0; kk < 4; ++kk) {
            int ch = (kk * 4 + g) ^ (s & 7);
            bf16x8 bf = *(const bf16x8*)&ksbuf[row * 128 + ch * 8];
            sf[fb] = __builtin_amdgcn_mfma_f32_16x16x32_bf16(qa[kk], bf, sf[fb], 0, 0, 0);
        }
    }
#pragma unroll
    for (int xb = 0; xb < 2; ++xb) {
        int i = xb * 16 + s;
        int keyrow = (i < 4) ? i : (qw + (i - 4) - 1);
        if (keyrow < 0) keyrow = 0;
        if (keyrow > 2047) keyrow = 2047;
        const u16* kr = kb + (size_t)keyrow * 512 + kvh * 128 + g * 8;
#pragma unroll
        for (int kk = 0; kk < 4; ++kk) {
            bf16x8 bf = *(const bf16x8*)&kr[kk * 32];
            sf[16 + xb] = __builtin_amdgcn_mfma_f32_16x16x32_bf16(qa[kk], bf, sf[16 + xb], 0, 0, 0);
        }
    }

    const float scale = 0.08838834764831845f;  // 1/sqrt(128)
    float mx[4] = {-1e30f, -1e30f, -1e30f, -1e30f};
#pragma unroll
    for (int fi = 0; fi < 18; ++fi)
#pragma unroll
        for (int r = 0; r < 4; ++r) {
            int q = g * 4 + r;
            int t = qw + q;
            bool ok;
            if (fi < 16) {
                int j = fi * 16 + s;
                ok = j < (t >> 3);
            } else {
                int i = (fi - 16) * 16 + s;
                if (i < 4) ok = (i <= t);
                else       ok = ((i - 4) == q) && ((t & 7) != 0) && (t >= 5);
            }
            float v = ok ? sf[fi][r] * scale : -1e30f;
            sf[fi][r] = v;
            mx[r] = fmaxf(mx[r], v);
        }
#pragma unroll
    for (int r = 0; r < 4; ++r)
#pragma unroll
        for (int off = 8; off; off >>= 1) mx[r] = fmaxf(mx[r], __shfl_xor(mx[r], off));

    float sm[4] = {0.f, 0.f, 0.f, 0.f};
#pragma unroll
    for (int fi = 0; fi < 18; ++fi)
#pragma unroll
        for (int r = 0; r < 4; ++r) {
            float p = __expf(sf[fi][r] - mx[r]);
            sf[fi][r] = p;
            sm[r] += p;
        }
#pragma unroll
    for (int r = 0; r < 4; ++r)
#pragma unroll
        for (int off = 8; off; off >>= 1) sm[r] += __shfl_xor(sm[r], off);
    float inv[4];
#pragma unroll
    for (int r = 0; r < 4; ++r) inv[r] = 1.f / sm[r];

    __syncthreads();

    u16* pbuf = ksbuf + w * 4096;
#pragma unroll
    for (int fi = 0; fi < 16; ++fi)
#pragma unroll
        for (int r = 0; r < 4; ++r) {
            int q = g * 4 + r;
            int c = fi * 16 + s;
            int blk = (c >> 3) ^ q;
            pbuf[q * 256 + (blk << 3) + (c & 7)] = f2b(sf[fi][r]);
        }
#pragma unroll
    for (int xb = 0; xb < 2; ++xb)
#pragma unroll
        for (int r = 0; r < 4; ++r)
            p_ext[w][g * 4 + r][xb * 16 + s] = sf[16 + xb][r];

    bf16x8 pa[8];
#pragma unroll
    for (int kk = 0; kk < 8; ++kk) {
        int blk = (kk * 4 + g) ^ s;
        pa[kk] = *(const bf16x8*)&pbuf[s * 256 + (blk << 3)];
    }
    f32x4 out[8];
#pragma unroll
    for (int f = 0; f < 8; ++f) out[f] = f32x4{0.f, 0.f, 0.f, 0.f};
#pragma unroll
    for (int f = 0; f < 8; ++f) {
        int row = f * 16 + s;
#pragma unroll
        for (int kk = 0; kk < 8; ++kk) {
            int ch = (kk * 4 + g) ^ (s & 7);
            bf16x8 vf = *(const bf16x8*)&vsbuf[row * 256 + ch * 8];
            out[f] = __builtin_amdgcn_mfma_f32_16x16x32_bf16(pa[kk], vf, out[f], 0, 0, 0);
        }
    }

    {
        float v4[4][8];
#pragma unroll
        for (int e = 0; e < 4; ++e)
#pragma unroll
            for (int f = 0; f < 8; ++f)
                v4[e][f] = b2f(vb[(size_t)e * 512 + kvh * 128 + f * 16 + s]);
#pragma unroll
        for (int r = 0; r < 4; ++r) {
            int q = g * 4 + r;
            int t = qw + q;
#pragma unroll
            for (int e = 0; e < 4; ++e) {
                float p = p_ext[w][q][e];
#pragma unroll
                for (int f = 0; f < 8; ++f) out[f][r] += p * v4[e][f];
            }
            float pp = p_ext[w][q][4 + q];
            int key = t - 1; if (key < 0) key = 0;
            const u16* vr = vb + (size_t)key * 512 + kvh * 128;
#pragma unroll
            for (int f = 0; f < 8; ++f) out[f][r] += pp * b2f(vr[f * 16 + s]);
        }
    }

#pragma unroll
    for (int f = 0; f < 8; ++f)
#pragma unroll
        for (int r = 0; r < 4; ++r) {
            int t = qw + g * 4 + r;
            aout[(size_t)t * 2048 + h * 128 + f * 16 + s] = f2b(out[f][r] * inv[r]);
        }
}

// ---------------------------------------------------------------------------
extern "C" void kernel_launch(void* const* d_in, const int* in_sizes, int n_in,
                              void* d_out, int out_size, void* d_ws, size_t ws_size,
                              hipStream_t stream) {
    const float* x   = (const float*)d_in[0];
    const float* fc  = (const float*)d_in[1];
    const float* wq  = (const float*)d_in[2];
    const float* wk  = (const float*)d_in[3];
    const float* wv  = (const float*)d_in[4];
    const float* wo  = (const float*)d_in[5];
    const float* alk = (const float*)d_in[6];
    const float* bk  = (const float*)d_in[7];
    const float* ck  = (const float*)d_in[8];
    const float* alv = (const float*)d_in[9];
    const float* bv  = (const float*)d_in[10];
    const float* cv  = (const float*)d_in[11];

    char* ws = (char*)d_ws;
    u16*   xb   = (u16*)(ws);                  //  8,388,608 B
    u16*   wcat = (u16*)(ws + 8388608);        // 12,582,912 B
    u16*   wob  = (u16*)(ws + 20971520);       //  8,388,608 B
    u16*   c1   = (u16*)(ws + 29360128);       // 12,582,912 B (bf16 now)
    u16*   qb   = (u16*)(ws + 54525952);       //  8,388,608 B
    u16*   kb   = (u16*)(ws + 62914560);       //  2,097,152 B
    u16*   vb   = (u16*)(ws + 65011712);       //  2,097,152 B
    u16*   kbc  = (u16*)(ws + 67108864);       //    262,144 B
    u16*   vbt  = (u16*)(ws + 67371008);       //    262,144 B
    u16*   aout = (u16*)(ws + 67633152);       //  8,388,608 B

    convert_kernel<<<14336, 256, 0, stream>>>(x, wq, wk, wv, wo, xb, wcat, wob);

    dim3 g1(3072 / 128, 2048 / 128);
    gemm_bt_kernel<1><<<g1, 512, 0, stream>>>(xb, wcat, (void*)c1, 2048, 3072, 2048);

    ssm_rope_kernel<<<8960, 256, 0, stream>>>(c1, fc, alk, bk, ck, alv, bv, cv, qb, kb, vb);

    compact_kernel<<<512, 256, 0, stream>>>(kb, vb, kbc, vbt);

    attn_kernel<<<256, 512, 0, stream>>>(qb, kb, vb, kbc, vbt, aout);

    dim3 g3(2048 / 128, 2048 / 128);
    gemm_bt_kernel<0><<<g3, 512, 0, stream>>>(aout, wob, d_out, 2048, 2048, 2048);
}